// Round 6
// baseline (49444.272 us; speedup 1.0000x reference)
//
#include <hip/hip_runtime.h>

// ============================================================================
// Two-level LSTM (char k-mer LSTM -> word LSTM), MI355X.
//
// Persistent multi-WG recurrence kernels, all worker WGs elected onto ONE XCD.
// Exchange protocol (R6):
//   - data plane: producer publishes its h-shard as tag-embedded 8B words
//     ((t+1)<<32 | f32bits) into a 256-deep rotating buffer using
//     global_atomic_swap_x2 (executed at TCC -> committed to shared XCD L2,
//     immune to the write-back-L1 trap that broke R5's plain stores).
//   - control plane: after `s_waitcnt vmcnt(0)` on the data swaps, ONE
//     global_atomic_swap tag per WG. Tag visible => data committed in L2.
//   - consumer: PER-WAVE gating. Wave w polls only the tags of the producers
//     owning its 64-element h-slice (4 tags char / 2 word, atomic-or-0),
//     then plain-loads its slice from the rotated buffer (first touch in
//     256 steps -> L1 miss -> L2 hit). Embedded tag verified per word;
//     mismatch -> single-shot atomic read (sound: tag => data at TCC).
//   - one parity-buffered barrier per step. Race-freedom: a WG publishes
//     tag t+1 only after ALL its waves passed their t gates, which
//     collectively cover ALL producers; hence tag t+1 from anyone implies
//     every WG finished reading part[par] for step t, and implies every
//     wave consumed tag t before slot t+2 overwrites it.
// ============================================================================

#define S_LEN 4096
#define TCH   16384
#define ALPHA 25
#define ECH   64
#define HR    256
#define DL    128
#define EW    128
#define HW    512
#define NWC   16
#define GRIDC 128
#define NWW   16
#define GRIDW 128
#define NBUF  256          // rotation depth

static __device__ __forceinline__ float fsigmoid(float x) {
  x = fminf(fmaxf(x, -30.f), 30.f);
  return __builtin_amdgcn_rcpf(1.0f + __expf(-x));
}
static __device__ __forceinline__ float ftanh(float x) {
  x = fminf(fmaxf(x, -15.f), 15.f);
  float e = __expf(2.0f * x);
  return 1.0f - 2.0f * __builtin_amdgcn_rcpf(e + 1.0f);
}

static __device__ __forceinline__ void barrier_lds() {
  asm volatile("s_waitcnt lgkmcnt(0)\n\ts_barrier" ::: "memory");
}
static __device__ __forceinline__ void waitcnt_vm0() {
  asm volatile("s_waitcnt vmcnt(0)" ::: "memory");
}
// Atomic or-0 with return: performed at the TCC, architecturally coherent.
static __device__ __forceinline__ unsigned long long atom_or_ret(
    unsigned long long* p) {
  unsigned long long v, zero = 0;
  asm volatile("global_atomic_or_x2 %0, %1, %2, off sc0\n\ts_waitcnt vmcnt(0)"
               : "=&v"(v) : "v"(p), "v"(zero) : "memory");
  return v;
}
// Atomic swap, no return: data lands at the TCC (shared L2).
static __device__ __forceinline__ void atom_swap(
    unsigned long long* p, unsigned long long v) {
  asm volatile("global_atomic_swap_x2 %0, %1, off" :: "v"(p), "v"(v) : "memory");
}

// Deadlock-free single-XCD role election (R4-proven).
static __device__ __forceinline__ int elect_role(int* el, int NW) {
  unsigned xcd;
  asm volatile("s_getreg_b32 %0, hwreg(HW_REG_XCC_ID)" : "=s"(xcd));
  xcd &= 7u;
  int r = __hip_atomic_fetch_add(&el[xcd], 1, __ATOMIC_RELAXED,
                                 __HIP_MEMORY_SCOPE_AGENT);
  if (r == NW - 1) {
    int exp = -1;
    __hip_atomic_compare_exchange_strong(&el[8], &exp, (int)xcd,
        __ATOMIC_RELAXED, __ATOMIC_RELAXED, __HIP_MEMORY_SCOPE_AGENT);
  }
  int w;
  while ((w = __hip_atomic_load(&el[8], __ATOMIC_RELAXED,
                                __HIP_MEMORY_SCOPE_AGENT)) < 0) {}
  if (w != (int)xcd) return -1;
  int rr = __hip_atomic_fetch_add(&el[9], 1, __ATOMIC_RELAXED,
                                  __HIP_MEMORY_SCOPE_AGENT);
  return (rr < NW) ? rr : -1;
}

__global__ void k_init(int* ec, int* ew) {
  int t = threadIdx.x;
  if (t < 10) ec[t] = (t == 8) ? -1 : 0;
  else if (t < 20) { int u = t - 10; ew[u] = (u == 8) ? -1 : 0; }
}

// ---------------------------------------------------------------------------
// K1a: char gate-input table.
// ---------------------------------------------------------------------------
__global__ void k_table(const float* __restrict__ Ec, const float* __restrict__ Wih,
                        const float* __restrict__ br, float* __restrict__ table) {
  __shared__ __align__(16) float e[ECH];
  int a = blockIdx.x, tid = threadIdx.x;
  if (tid < ECH) e[tid] = Ec[a * ECH + tid];
  __syncthreads();
  for (int row = tid; row < 4 * HR; row += 256) {
    const float4* w = (const float4*)(Wih + row * ECH);
    const float4* e4 = (const float4*)e;
    float acc = 0.f;
#pragma unroll
    for (int j = 0; j < ECH / 4; ++j) {
      float4 wv = w[j], ev = e4[j];
      acc += wv.x * ev.x + wv.y * ev.y + wv.z * ev.z + wv.w * ev.w;
    }
    table[a * (4 * HR) + row] = acc + br[row];
  }
}

// ---------------------------------------------------------------------------
// K1b: permute W_ih_w k-major; p = wg*128 + rloc, rloc = gate*32 + unit.
// ---------------------------------------------------------------------------
__global__ void k_permw(const float* __restrict__ Wihw, const float* __restrict__ bw,
                        float* __restrict__ WT, float* __restrict__ bperm) {
  int e = blockIdx.x * 256 + threadIdx.x;
  int p = e >> 8, k = e & 255;
  int wgp = p >> 7, rl = p & 127, gate = rl >> 5, unit = rl & 31;
  int R = gate * HW + wgp * 32 + unit;
  WT[k * (4 * HW) + p] = Wihw[R * (EW + DL) + k];
  if (k == 0) bperm[p] = bw[R];
}

// ---------------------------------------------------------------------------
// K2: persistent char LSTM. 16 WGs x 256 threads (4 waves) on one XCD.
// Wave w consumes h slice [64w, 64w+64) = producers 4w..4w+3.
// ---------------------------------------------------------------------------
__global__ __launch_bounds__(256) void k_char_lstm(
    const int* __restrict__ char_ids, const float* __restrict__ Whh,
    const float* __restrict__ table, unsigned long long* __restrict__ tags,
    unsigned long long* __restrict__ hbuf, int* __restrict__ elect,
    float* __restrict__ h_word)
{
  __shared__ int role_sh;
  if (threadIdx.x == 0) role_sh = elect_role(elect, NWC);
  __syncthreads();
  const int wg = role_sh;
  if (wg < 0) return;

  const int tid = threadIdx.x;
  const int wave = tid >> 6, lane = tid & 63;
  const int R = (lane >> 4) * HR + wg * 16 + (lane & 15);
  float4 wreg[16];
  {
    const float4* wp = (const float4*)(Whh + R * HR + wave * 64);
#pragma unroll
    for (int j = 0; j < 16; ++j) wreg[j] = wp[j];
  }
  __shared__ __align__(16) float tab[ALPHA * 64];
  __shared__ __align__(16) float hsl[4][64];     // per-wave h slice
  __shared__ __align__(16) float part[2][4][64]; // parity-buffered partials
  for (int i = tid; i < ALPHA * 64; i += 256) {
    int chh = i >> 6, r = i & 63;
    int Rr = (r >> 4) * HR + wg * 16 + (r & 15);
    tab[i] = table[chh * (4 * HR) + Rr];
  }
  hsl[wave][lane] = 0.f;
  float creg = 0.f;                      // cell state: wave0 lanes<16
  __syncthreads();

#pragma unroll 1
  for (int t = 0; t < TCH; ++t) {
    int ch = char_ids[t];
    if (t > 0) {
      // per-wave gate: poll tags of this wave's 4 producers
      unsigned long long want = (unsigned long long)t;
      unsigned long long* tp =
          tags + ((((t - 1) & 1) * 16) + 4 * wave + (lane & 3)) * 8;
      bool pend = lane < 4;
      while (__any(pend)) {
        if (pend) pend = (atom_or_ret(tp) != want);
      }
      // slice load: one tag-embedded word per lane, rotated first-touch
      int rb = (t - 1) & (NBUF - 1);
      unsigned long long* sb = hbuf + rb * HR + wave * 64 + lane;
      unsigned long long d = *sb;
      if ((unsigned)(d >> 32) != (unsigned)t) d = atom_or_ret(sb);
      hsl[wave][lane] = __uint_as_float((unsigned)d);
      // same-wave LDS write->read: compiler-inserted lgkmcnt, no barrier.
    }
    const float4* hp = (const float4*)hsl[wave];
    float a0 = 0.f, a1 = 0.f, a2 = 0.f, a3 = 0.f;
#pragma unroll
    for (int j = 0; j < 4; ++j) {
      float4 h0 = hp[4*j+0], h1 = hp[4*j+1], h2 = hp[4*j+2], h3 = hp[4*j+3];
      float4 w0 = wreg[4*j+0], w1 = wreg[4*j+1], w2 = wreg[4*j+2], w3 = wreg[4*j+3];
      a0 += w0.x*h0.x + w0.y*h0.y + w0.z*h0.z + w0.w*h0.w;
      a1 += w1.x*h1.x + w1.y*h1.y + w1.z*h1.z + w1.w*h1.w;
      a2 += w2.x*h2.x + w2.y*h2.y + w2.z*h2.z + w2.w*h2.w;
      a3 += w3.x*h3.x + w3.y*h3.y + w3.z*h3.z + w3.w*h3.w;
    }
    const int par = t & 1;
    part[par][wave][lane] = (a0 + a1) + (a2 + a3);
    barrier_lds();                       // single barrier per step
    if (wave == 0) {
      float z = ((part[par][0][lane] + part[par][1][lane]) +
                 (part[par][2][lane] + part[par][3][lane])) + tab[ch * 64 + lane];
      int u = lane & 15;
      float zi = __shfl(z, u,      64);
      float zf = __shfl(z, u + 16, 64);
      float zg = __shfl(z, u + 32, 64);
      float zo = __shfl(z, u + 48, 64);
      float h = 0.f;
      if (lane < 16) {
        float ig = fsigmoid(zi), fg = fsigmoid(zf), og = fsigmoid(zo);
        float gg = ftanh(zg);
        creg = fg * creg + ig * gg;
        h = og * ftanh(creg);
        unsigned long long pv =
            (((unsigned long long)(unsigned)(t + 1)) << 32) |
            (unsigned long long)__float_as_uint(h);
        atom_swap(hbuf + (t & (NBUF - 1)) * HR + wg * 16 + lane, pv);
      }
      waitcnt_vm0();                     // data at TCC ...
      if (lane == 0)                     // ... before the tag swap
        atom_swap(tags + (((t & 1) * 16) + wg) * 8,
                  (unsigned long long)(t + 1));
      if ((t & 3) == 3 && lane < 16)
        h_word[(t >> 2) * HR + wg * 16 + lane] = h;
    }
  }
}

// ---------------------------------------------------------------------------
// K3a: latent = tanh(h_word @ W_lat^T + b_lat).
// ---------------------------------------------------------------------------
__global__ __launch_bounds__(128) void k_latent(
    const float* __restrict__ hw, const float* __restrict__ Wlat,
    const float* __restrict__ blat, float* __restrict__ lat)
{
  int t = blockIdx.x, d = threadIdx.x;
  __shared__ __align__(16) float hh[HR];
  ((float2*)hh)[d] = ((const float2*)(hw + t * HR))[d];
  __syncthreads();
  const float4* w = (const float4*)(Wlat + d * HR);
  const float4* h4 = (const float4*)hh;
  float acc = 0.f;
#pragma unroll 8
  for (int j = 0; j < HR / 4; ++j) {
    float4 wv = w[j], hv = h4[j];
    acc += wv.x * hv.x + wv.y * hv.y + wv.z * hv.z + wv.w * hv.w;
  }
  lat[t * DL + d] = tanhf(acc + blat[d]);
}

// ---------------------------------------------------------------------------
// K3b: Xw[t][p] = bperm[p] + concat(E_word[wid[t]], latent[t]) · W row(p)
// ---------------------------------------------------------------------------
__global__ __launch_bounds__(256) void k_xw(
    const float* __restrict__ Ew, const int* __restrict__ wid,
    const float* __restrict__ lat, const float* __restrict__ WT,
    const float* __restrict__ bperm, float* __restrict__ Xw)
{
  int tblk = blockIdx.x, pblk = blockIdx.y;
  int tid = threadIdx.x;
  int p = pblk * 256 + tid;
  __shared__ __align__(16) float xt[32][256];
  int t0 = tblk * 32;
  for (int i = tid; i < 32 * 256; i += 256) {
    int tl = i >> 8, e = i & 255;
    int t = t0 + tl;
    float v;
    if (e < 128) v = Ew[wid[t] * EW + e];
    else         v = lat[t * DL + (e - 128)];
    xt[tl][e] = v;
  }
  __syncthreads();
  float acc[32];
#pragma unroll
  for (int i = 0; i < 32; ++i) acc[i] = 0.f;
  for (int k = 0; k < 256; k += 4) {
    float w0 = WT[(k + 0) * (4 * HW) + p];
    float w1 = WT[(k + 1) * (4 * HW) + p];
    float w2 = WT[(k + 2) * (4 * HW) + p];
    float w3 = WT[(k + 3) * (4 * HW) + p];
#pragma unroll
    for (int tl = 0; tl < 32; ++tl) {
      float4 x4 = *(const float4*)&xt[tl][k];
      acc[tl] += w0 * x4.x + w1 * x4.y + w2 * x4.z + w3 * x4.w;
    }
  }
  float b = bperm[p];
#pragma unroll
  for (int tl = 0; tl < 32; ++tl)
    Xw[(t0 + tl) * (4 * HW) + p] = acc[tl] + b;
}

// ---------------------------------------------------------------------------
// K4: persistent word LSTM. 16 WGs x 1024 threads (16 waves) on one XCD.
// Thread: kseg = tid>>7 (64-k segment), rloc = tid&127 (gate*32+unit).
// Wave w consumes h slice [64*(w>>1), +64) = producers 2*(w>>1), 2*(w>>1)+1.
// ---------------------------------------------------------------------------
__global__ __launch_bounds__(1024) void k_word_lstm(
    const float* __restrict__ Whh, const float* __restrict__ Xw,
    unsigned long long* __restrict__ tags, unsigned long long* __restrict__ hbuf,
    int* __restrict__ elect, float* __restrict__ out)
{
  __shared__ int role_sh;
  if (threadIdx.x == 0) role_sh = elect_role(elect, NWW);
  __syncthreads();
  const int wg = role_sh;
  if (wg < 0) return;

  const int tid = threadIdx.x;
  const int wave = tid >> 6, lane = tid & 63;
  const int kseg = tid >> 7, rloc = tid & 127;
  const int gate = rloc >> 5, unit = rloc & 31;
  const int R = gate * HW + wg * 32 + unit;
  float4 wreg[16];
  {
    const float4* wp = (const float4*)(Whh + R * HW + kseg * 64);
#pragma unroll
    for (int j = 0; j < 16; ++j) wreg[j] = wp[j];
  }
  __shared__ __align__(16) float hsl[16][64];       // per-wave h slice
  __shared__ __align__(16) float part[2][8][128];   // parity-buffered
  hsl[wave][lane] = 0.f;
  float creg = 0.f;                      // cell state: wave0 lanes<32
  __syncthreads();
  float xv1 = 0.f, xv2 = 0.f;
  if (wave == 0) {
    xv1 = Xw[wg * 128 + lane];
    xv2 = Xw[wg * 128 + 64 + lane];
  }

#pragma unroll 1
  for (int t = 0; t < S_LEN; ++t) {
    float xn1 = 0.f, xn2 = 0.f;
    if (wave == 0) {
      int tt = (t + 1 < S_LEN) ? (t + 1) : t;
      xn1 = Xw[tt * (4 * HW) + wg * 128 + lane];
      xn2 = Xw[tt * (4 * HW) + wg * 128 + 64 + lane];
    }
    if (t > 0) {
      unsigned long long want = (unsigned long long)t;
      unsigned long long* tp =
          tags + ((((t - 1) & 1) * 16) + 2 * (wave >> 1) + (lane & 1)) * 8;
      bool pend = lane < 2;
      while (__any(pend)) {
        if (pend) pend = (atom_or_ret(tp) != want);
      }
      int rb = (t - 1) & (NBUF - 1);
      unsigned long long* sb = hbuf + rb * HW + (wave >> 1) * 64 + lane;
      unsigned long long d = *sb;
      if ((unsigned)(d >> 32) != (unsigned)t) d = atom_or_ret(sb);
      hsl[wave][lane] = __uint_as_float((unsigned)d);
    }
    const float4* hp = (const float4*)hsl[wave];
    float a0 = 0.f, a1 = 0.f, a2 = 0.f, a3 = 0.f;
#pragma unroll
    for (int j = 0; j < 4; ++j) {
      float4 h0 = hp[4*j+0], h1 = hp[4*j+1], h2 = hp[4*j+2], h3 = hp[4*j+3];
      float4 w0 = wreg[4*j+0], w1 = wreg[4*j+1], w2 = wreg[4*j+2], w3 = wreg[4*j+3];
      a0 += w0.x*h0.x + w0.y*h0.y + w0.z*h0.z + w0.w*h0.w;
      a1 += w1.x*h1.x + w1.y*h1.y + w1.z*h1.z + w1.w*h1.w;
      a2 += w2.x*h2.x + w2.y*h2.y + w2.z*h2.z + w2.w*h2.w;
      a3 += w3.x*h3.x + w3.y*h3.y + w3.z*h3.z + w3.w*h3.w;
    }
    const int par = t & 1;
    part[par][kseg][rloc] = (a0 + a1) + (a2 + a3);
    barrier_lds();
    if (wave == 0) {
      float zl = 0.f, z2 = 0.f;
#pragma unroll
      for (int s = 0; s < 8; ++s) {
        zl += part[par][s][lane];
        z2 += part[par][s][64 + lane];
      }
      zl += xv1; z2 += xv2;
      int u = lane & 31;
      float zf = __shfl(zl, u + 32, 64);
      float zo = __shfl(z2, u + 32, 64);
      float h = 0.f;
      if (lane < 32) {
        float ig = fsigmoid(zl), fg = fsigmoid(zf), og = fsigmoid(zo);
        float gg = ftanh(z2);
        creg = fg * creg + ig * gg;
        h = og * ftanh(creg);
        unsigned long long pv =
            (((unsigned long long)(unsigned)(t + 1)) << 32) |
            (unsigned long long)__float_as_uint(h);
        atom_swap(hbuf + (t & (NBUF - 1)) * HW + wg * 32 + lane, pv);
      }
      waitcnt_vm0();
      if (lane == 0)
        atom_swap(tags + (((t & 1) * 16) + wg) * 8,
                  (unsigned long long)(t + 1));
      if (lane < 32) out[t * HW + wg * 32 + lane] = h;
      xv1 = xn1; xv2 = xn2;
    }
  }
}

// ---------------------------------------------------------------------------
extern "C" void kernel_launch(void* const* d_in, const int* in_sizes, int n_in,
                              void* d_out, int out_size, void* d_ws, size_t ws_size,
                              hipStream_t stream) {
  const float* E_char = (const float*)d_in[0];
  const float* W_ih_r = (const float*)d_in[1];
  const float* W_hh_r = (const float*)d_in[2];
  const float* b_r    = (const float*)d_in[3];
  const float* W_lat  = (const float*)d_in[4];
  const float* b_lat  = (const float*)d_in[5];
  const float* E_word = (const float*)d_in[6];
  const float* W_ih_w = (const float*)d_in[7];
  const float* W_hh_w = (const float*)d_in[8];
  const float* b_w    = (const float*)d_in[9];
  const int* word_ids = (const int*)d_in[10];
  const int* char_ids = (const int*)d_in[11];

  char* ws = (char*)d_ws;
  float*              tableR = (float*)(ws + 0x000000);              // 100 KB
  unsigned long long* tagC   = (unsigned long long*)(ws + 0x020000); // 2 KB
  unsigned long long* tagW   = (unsigned long long*)(ws + 0x021000); // 2 KB
  int*                electC = (int*)(ws + 0x022000);
  int*                electW = (int*)(ws + 0x022100);
  unsigned long long* hbufC  = (unsigned long long*)(ws + 0x030000); // 512 KB
  unsigned long long* hbufW  = (unsigned long long*)(ws + 0x0B0000); // 1 MB
  float*              h_word = (float*)(ws + 0x1B0000);              // 4 MB
  float*              latent = (float*)(ws + 0x5B0000);              // 2 MB
  float*              WT     = (float*)(ws + 0x7B0000);              // 2 MB
  float*              bperm  = (float*)(ws + 0x9B0000);              // 8 KB
  float*              Xw     = (float*)(ws + 0xA00000);              // 32 MB
  float* out = (float*)d_out;

  hipLaunchKernelGGL(k_init,      dim3(1),      dim3(64),   0, stream,
                     electC, electW);
  hipLaunchKernelGGL(k_table,     dim3(ALPHA),  dim3(256),  0, stream,
                     E_char, W_ih_r, b_r, tableR);
  hipLaunchKernelGGL(k_permw,     dim3(2048),   dim3(256),  0, stream,
                     W_ih_w, b_w, WT, bperm);
  hipLaunchKernelGGL(k_char_lstm, dim3(GRIDC),  dim3(256),  0, stream,
                     char_ids, W_hh_r, tableR, tagC, hbufC, electC, h_word);
  hipLaunchKernelGGL(k_latent,    dim3(S_LEN),  dim3(128),  0, stream,
                     h_word, W_lat, b_lat, latent);
  hipLaunchKernelGGL(k_xw,        dim3(128, 8), dim3(256),  0, stream,
                     E_word, word_ids, latent, WT, bperm, Xw);
  hipLaunchKernelGGL(k_word_lstm, dim3(GRIDW),  dim3(1024), 0, stream,
                     W_hh_w, Xw, tagW, hbufW, electW, out);
}

// Round 7
// 26319.693 us; speedup vs baseline: 1.8786x; 1.8786x over previous
//
#include <hip/hip_runtime.h>

// ============================================================================
// Two-level LSTM (char k-mer LSTM -> word LSTM), MI355X.
//
// Persistent multi-WG recurrence kernels, all worker WGs elected onto ONE XCD
// (pigeonhole election, HW_REG_XCC_ID). Exchange = R4's proven single-hop
// protocol: tagged 8-byte slots ((t+1)<<32 | f32bits(h)), parity
// double-buffered, atomic swap publish / atomic or-0 poll (atomics execute at
// the TCC -- the only cross-CU-coherent primitive, per R2/R3).
//
// R7 fixes over R4:
//  1. PRIVATE PER-CONSUMER-WG REPLICAS of the slot array. R4 had every
//     consumer WG polling the same lines (256 RMWs/line/round serialized at
//     the TCC ~2500 cyc). Now producer wave0's 64 lanes fan the 16 tagged
//     words out to all replicas (char: 4 swap insts, word: 8); each line is
//     polled by exactly one wave's 16 lanes.
//  2. __launch_bounds__(..., 1): every prior round spilled wreg[16] (64
//     VGPRs) to scratch (VGPR_Count 52-56!) and re-loaded it每 step through
//     L1/L2. min-waves=1 lifts the allocator cap to 512 VGPRs.
//
// Race-freedom (unchanged from R4): WG g publishes tag t+1 only after all its
// waves wrote part[par] (post-poll of t) and passed the barrier; consumer WGs
// collectively poll ALL producers, so any tag t+2 implies every WG consumed
// t -- overwriting parity (t&1) is safe. Poll's vmcnt(0) drains prior
// publishes, so same-lane same-address swaps never reorder across parities.
// ============================================================================

#define S_LEN 4096
#define TCH   16384
#define ALPHA 25
#define ECH   64
#define HR    256
#define DL    128
#define EW    128
#define HW    512
#define NWC   16           // char worker WGs (16 units each)
#define GRIDC 128
#define NWW   32           // word worker WGs (16 units each)
#define GRIDW 256

static __device__ __forceinline__ float fsigmoid(float x) {
  x = fminf(fmaxf(x, -30.f), 30.f);
  return __builtin_amdgcn_rcpf(1.0f + __expf(-x));
}
static __device__ __forceinline__ float ftanh(float x) {
  x = fminf(fmaxf(x, -15.f), 15.f);
  float e = __expf(2.0f * x);
  return 1.0f - 2.0f * __builtin_amdgcn_rcpf(e + 1.0f);
}

static __device__ __forceinline__ void barrier_lds() {
  asm volatile("s_waitcnt lgkmcnt(0)\n\ts_barrier" ::: "memory");
}
// Atomic or-0 with return: executed at the TCC, architecturally coherent.
static __device__ __forceinline__ unsigned long long atom_or_ret(
    unsigned long long* p) {
  unsigned long long v, zero = 0;
  asm volatile("global_atomic_or_x2 %0, %1, %2, off sc0\n\ts_waitcnt vmcnt(0)"
               : "=&v"(v) : "v"(p), "v"(zero) : "memory");
  return v;
}
// Atomic swap, no return: fire-and-forget commit to the shared XCD L2.
static __device__ __forceinline__ void atom_swap(
    unsigned long long* p, unsigned long long v) {
  asm volatile("global_atomic_swap_x2 %0, %1, off" :: "v"(p), "v"(v) : "memory");
}

// Deadlock-free single-XCD role election (R4-proven).
static __device__ __forceinline__ int elect_role(int* el, int NW) {
  unsigned xcd;
  asm volatile("s_getreg_b32 %0, hwreg(HW_REG_XCC_ID)" : "=s"(xcd));
  xcd &= 7u;
  int r = __hip_atomic_fetch_add(&el[xcd], 1, __ATOMIC_RELAXED,
                                 __HIP_MEMORY_SCOPE_AGENT);
  if (r == NW - 1) {
    int exp = -1;
    __hip_atomic_compare_exchange_strong(&el[8], &exp, (int)xcd,
        __ATOMIC_RELAXED, __ATOMIC_RELAXED, __HIP_MEMORY_SCOPE_AGENT);
  }
  int w;
  while ((w = __hip_atomic_load(&el[8], __ATOMIC_RELAXED,
                                __HIP_MEMORY_SCOPE_AGENT)) < 0) {}
  if (w != (int)xcd) return -1;
  int rr = __hip_atomic_fetch_add(&el[9], 1, __ATOMIC_RELAXED,
                                  __HIP_MEMORY_SCOPE_AGENT);
  return (rr < NW) ? rr : -1;
}

__global__ void k_init(int* ec, int* ew) {
  int t = threadIdx.x;
  if (t < 10) ec[t] = (t == 8) ? -1 : 0;
  else if (t < 20) { int u = t - 10; ew[u] = (u == 8) ? -1 : 0; }
}

// ---------------------------------------------------------------------------
// K1a: char gate-input table: table[a][row] = b_r[row] + E_char[a,:]·W_ih_r[row,:]
// ---------------------------------------------------------------------------
__global__ void k_table(const float* __restrict__ Ec, const float* __restrict__ Wih,
                        const float* __restrict__ br, float* __restrict__ table) {
  __shared__ __align__(16) float e[ECH];
  int a = blockIdx.x, tid = threadIdx.x;
  if (tid < ECH) e[tid] = Ec[a * ECH + tid];
  __syncthreads();
  for (int row = tid; row < 4 * HR; row += 256) {
    const float4* w = (const float4*)(Wih + row * ECH);
    const float4* e4 = (const float4*)e;
    float acc = 0.f;
#pragma unroll
    for (int j = 0; j < ECH / 4; ++j) {
      float4 wv = w[j], ev = e4[j];
      acc += wv.x * ev.x + wv.y * ev.y + wv.z * ev.z + wv.w * ev.w;
    }
    table[a * (4 * HR) + row] = acc + br[row];
  }
}

// ---------------------------------------------------------------------------
// K1b: permute W_ih_w k-major: WT[k][p], p = wg*64 + (gate*16 + unit).
// ---------------------------------------------------------------------------
__global__ void k_permw(const float* __restrict__ Wihw, const float* __restrict__ bw,
                        float* __restrict__ WT, float* __restrict__ bperm) {
  int e = blockIdx.x * 256 + threadIdx.x;
  int p = e >> 8, k = e & 255;
  int r = p & 63, wgp = p >> 6;
  int R = (r >> 4) * HW + wgp * 16 + (r & 15);
  WT[k * (4 * HW) + p] = Wihw[R * (EW + DL) + k];
  if (k == 0) bperm[p] = bw[R];
}

// ---------------------------------------------------------------------------
// K2: persistent char LSTM. 16 WGs x 256 threads on one XCD.
// slots layout: [parity][replica=consumer wg][slot 0..255], 8 B each.
// Line (g, 16 slots of producer p) is polled only by WG g's wave p>>2.
// ---------------------------------------------------------------------------
__global__ __launch_bounds__(256, 1) void k_char_lstm(
    const int* __restrict__ char_ids, const float* __restrict__ Whh,
    const float* __restrict__ table, unsigned long long* __restrict__ slots,
    int* __restrict__ elect, float* __restrict__ h_word)
{
  __shared__ int role_sh;
  if (threadIdx.x == 0) role_sh = elect_role(elect, NWC);
  __syncthreads();
  const int wg = role_sh;
  if (wg < 0) return;

  const int tid = threadIdx.x;
  const int wave = tid >> 6, lane = tid & 63;
  const int R = (lane >> 4) * HR + wg * 16 + (lane & 15);
  float4 wreg[16];
  {
    const float4* wp = (const float4*)(Whh + R * HR + wave * 64);
#pragma unroll
    for (int j = 0; j < 16; ++j) wreg[j] = wp[j];
  }
  __shared__ __align__(16) float tab[ALPHA * 64];
  __shared__ __align__(16) float hst[4][64];
  __shared__ __align__(16) float part[2][4][64];
  for (int i = tid; i < ALPHA * 64; i += 256) {
    int chh = i >> 6, r = i & 63;
    int Rr = (r >> 4) * HR + wg * 16 + (r & 15);
    tab[i] = table[chh * (4 * HR) + Rr];
  }
  hst[wave][lane] = 0.f;
  float creg = 0.f;                      // cell state: wave0 lanes<16
  __syncthreads();

#pragma unroll 1
  for (int t = 0; t < TCH; ++t) {
    int ch = char_ids[t];
    if (t > 0) {
      // poll own private replica; tag+data in one atomic (single hop)
      unsigned long long* sl =
          slots + ((t - 1) & 1) * (NWC * HR) + wg * HR + tid;
      unsigned long long v;
      do { v = atom_or_ret(sl); } while ((unsigned)(v >> 32) != (unsigned)t);
      hst[wave][lane] = __uint_as_float((unsigned)v);
      // same-wave LDS write->read: compiler-inserted lgkmcnt, no barrier.
    }
    const float4* hp = (const float4*)hst[wave];
    float a0 = 0.f, a1 = 0.f, a2 = 0.f, a3 = 0.f;
#pragma unroll
    for (int j = 0; j < 4; ++j) {
      float4 h0 = hp[4*j+0], h1 = hp[4*j+1], h2 = hp[4*j+2], h3 = hp[4*j+3];
      float4 w0 = wreg[4*j+0], w1 = wreg[4*j+1], w2 = wreg[4*j+2], w3 = wreg[4*j+3];
      a0 += w0.x*h0.x + w0.y*h0.y + w0.z*h0.z + w0.w*h0.w;
      a1 += w1.x*h1.x + w1.y*h1.y + w1.z*h1.z + w1.w*h1.w;
      a2 += w2.x*h2.x + w2.y*h2.y + w2.z*h2.z + w2.w*h2.w;
      a3 += w3.x*h3.x + w3.y*h3.y + w3.z*h3.z + w3.w*h3.w;
    }
    const int par = t & 1;
    part[par][wave][lane] = (a0 + a1) + (a2 + a3);
    barrier_lds();                       // single barrier per step
    if (wave == 0) {
      float z = ((part[par][0][lane] + part[par][1][lane]) +
                 (part[par][2][lane] + part[par][3][lane])) + tab[ch * 64 + lane];
      int u = lane & 15;
      float zi = __shfl(z, u,      64);
      float zf = __shfl(z, u + 16, 64);
      float zg = __shfl(z, u + 32, 64);
      float zo = __shfl(z, u + 48, 64);
      float h = 0.f;
      unsigned long long pv = 0;
      if (lane < 16) {
        float ig = fsigmoid(zi), fg = fsigmoid(zf), og = fsigmoid(zo);
        float gg = ftanh(zg);
        creg = fg * creg + ig * gg;
        h = og * ftanh(creg);
        pv = (((unsigned long long)(unsigned)(t + 1)) << 32) |
             (unsigned long long)__float_as_uint(h);
      }
      // broadcast the 16 tagged words to all 64 lanes, fan out to replicas
      unsigned long long pvb = __shfl(pv, lane & 15, 64);
      unsigned long long* pb =
          slots + par * (NWC * HR) + (lane >> 4) * HR + wg * 16 + (lane & 15);
      atom_swap(pb,           pvb);      // replicas lane>>4 + {0,4,8,12}
      atom_swap(pb +  4 * HR, pvb);
      atom_swap(pb +  8 * HR, pvb);
      atom_swap(pb + 12 * HR, pvb);
      if ((t & 3) == 3 && lane < 16)
        h_word[(t >> 2) * HR + wg * 16 + lane] = h;
    }
  }
}

// ---------------------------------------------------------------------------
// K3a: latent = tanh(h_word @ W_lat^T + b_lat).
// ---------------------------------------------------------------------------
__global__ __launch_bounds__(128) void k_latent(
    const float* __restrict__ hw, const float* __restrict__ Wlat,
    const float* __restrict__ blat, float* __restrict__ lat)
{
  int t = blockIdx.x, d = threadIdx.x;
  __shared__ __align__(16) float hh[HR];
  ((float2*)hh)[d] = ((const float2*)(hw + t * HR))[d];
  __syncthreads();
  const float4* w = (const float4*)(Wlat + d * HR);
  const float4* h4 = (const float4*)hh;
  float acc = 0.f;
#pragma unroll 8
  for (int j = 0; j < HR / 4; ++j) {
    float4 wv = w[j], hv = h4[j];
    acc += wv.x * hv.x + wv.y * hv.y + wv.z * hv.z + wv.w * hv.w;
  }
  lat[t * DL + d] = tanhf(acc + blat[d]);
}

// ---------------------------------------------------------------------------
// K3b: Xw[t][p] = bperm[p] + concat(E_word[wid[t]], latent[t]) · W row(p)
// ---------------------------------------------------------------------------
__global__ __launch_bounds__(256) void k_xw(
    const float* __restrict__ Ew, const int* __restrict__ wid,
    const float* __restrict__ lat, const float* __restrict__ WT,
    const float* __restrict__ bperm, float* __restrict__ Xw)
{
  int tblk = blockIdx.x, pblk = blockIdx.y;
  int tid = threadIdx.x;
  int p = pblk * 256 + tid;
  __shared__ __align__(16) float xt[32][256];
  int t0 = tblk * 32;
  for (int i = tid; i < 32 * 256; i += 256) {
    int tl = i >> 8, e = i & 255;
    int t = t0 + tl;
    float v;
    if (e < 128) v = Ew[wid[t] * EW + e];
    else         v = lat[t * DL + (e - 128)];
    xt[tl][e] = v;
  }
  __syncthreads();
  float acc[32];
#pragma unroll
  for (int i = 0; i < 32; ++i) acc[i] = 0.f;
  for (int k = 0; k < 256; k += 4) {
    float w0 = WT[(k + 0) * (4 * HW) + p];
    float w1 = WT[(k + 1) * (4 * HW) + p];
    float w2 = WT[(k + 2) * (4 * HW) + p];
    float w3 = WT[(k + 3) * (4 * HW) + p];
#pragma unroll
    for (int tl = 0; tl < 32; ++tl) {
      float4 x4 = *(const float4*)&xt[tl][k];
      acc[tl] += w0 * x4.x + w1 * x4.y + w2 * x4.z + w3 * x4.w;
    }
  }
  float b = bperm[p];
#pragma unroll
  for (int tl = 0; tl < 32; ++tl)
    Xw[(t0 + tl) * (4 * HW) + p] = acc[tl] + b;
}

// ---------------------------------------------------------------------------
// K4: persistent word LSTM. 32 WGs x 512 threads (8 waves) on one XCD.
// Wave w = k-segment [64w, 64w+64); lane: gate=lane>>4, unit=lane&15.
// slots: [parity][replica=consumer wg 0..31][slot 0..511].
// ---------------------------------------------------------------------------
__global__ __launch_bounds__(512, 1) void k_word_lstm(
    const float* __restrict__ Whh, const float* __restrict__ Xw,
    unsigned long long* __restrict__ slots, int* __restrict__ elect,
    float* __restrict__ out)
{
  __shared__ int role_sh;
  if (threadIdx.x == 0) role_sh = elect_role(elect, NWW);
  __syncthreads();
  const int wg = role_sh;
  if (wg < 0) return;

  const int tid = threadIdx.x;
  const int wave = tid >> 6, lane = tid & 63;
  const int R = (lane >> 4) * HW + wg * 16 + (lane & 15);
  float4 wreg[16];
  {
    const float4* wp = (const float4*)(Whh + R * HW + wave * 64);
#pragma unroll
    for (int j = 0; j < 16; ++j) wreg[j] = wp[j];
  }
  __shared__ __align__(16) float hst[8][64];
  __shared__ __align__(16) float part[2][8][64];
  hst[wave][lane] = 0.f;
  float creg = 0.f;                      // cell state: wave0 lanes<16
  __syncthreads();
  float xv = 0.f;
  if (wave == 0) xv = Xw[wg * 64 + lane];

#pragma unroll 1
  for (int t = 0; t < S_LEN; ++t) {
    float xn = 0.f;
    if (wave == 0) {                     // prefetch next x-slice
      int tt = (t + 1 < S_LEN) ? (t + 1) : t;
      xn = Xw[tt * (4 * HW) + wg * 64 + lane];
    }
    if (t > 0) {
      unsigned long long* sl =
          slots + ((t - 1) & 1) * (NWW * HW) + wg * HW + tid;
      unsigned long long v;
      do { v = atom_or_ret(sl); } while ((unsigned)(v >> 32) != (unsigned)t);
      hst[wave][lane] = __uint_as_float((unsigned)v);
    }
    const float4* hp = (const float4*)hst[wave];
    float a0 = 0.f, a1 = 0.f, a2 = 0.f, a3 = 0.f;
#pragma unroll
    for (int j = 0; j < 4; ++j) {
      float4 h0 = hp[4*j+0], h1 = hp[4*j+1], h2 = hp[4*j+2], h3 = hp[4*j+3];
      float4 w0 = wreg[4*j+0], w1 = wreg[4*j+1], w2 = wreg[4*j+2], w3 = wreg[4*j+3];
      a0 += w0.x*h0.x + w0.y*h0.y + w0.z*h0.z + w0.w*h0.w;
      a1 += w1.x*h1.x + w1.y*h1.y + w1.z*h1.z + w1.w*h1.w;
      a2 += w2.x*h2.x + w2.y*h2.y + w2.z*h2.z + w2.w*h2.w;
      a3 += w3.x*h3.x + w3.y*h3.y + w3.z*h3.z + w3.w*h3.w;
    }
    const int par = t & 1;
    part[par][wave][lane] = (a0 + a1) + (a2 + a3);
    barrier_lds();
    if (wave == 0) {
      float z = (((part[par][0][lane] + part[par][1][lane]) +
                  (part[par][2][lane] + part[par][3][lane])) +
                 ((part[par][4][lane] + part[par][5][lane]) +
                  (part[par][6][lane] + part[par][7][lane]))) + xv;
      int u = lane & 15;
      float zi = __shfl(z, u,      64);
      float zf = __shfl(z, u + 16, 64);
      float zg = __shfl(z, u + 32, 64);
      float zo = __shfl(z, u + 48, 64);
      float h = 0.f;
      unsigned long long pv = 0;
      if (lane < 16) {
        float ig = fsigmoid(zi), fg = fsigmoid(zf), og = fsigmoid(zo);
        float gg = ftanh(zg);
        creg = fg * creg + ig * gg;
        h = og * ftanh(creg);
        pv = (((unsigned long long)(unsigned)(t + 1)) << 32) |
             (unsigned long long)__float_as_uint(h);
      }
      unsigned long long pvb = __shfl(pv, lane & 15, 64);
      unsigned long long* pb =
          slots + par * (NWW * HW) + (lane >> 4) * HW + wg * 16 + (lane & 15);
#pragma unroll
      for (int i = 0; i < 8; ++i)        // replicas lane>>4 + 4*i
        atom_swap(pb + (4 * i) * HW, pvb);
      if (lane < 16) out[t * HW + wg * 16 + lane] = h;
      xv = xn;
    }
  }
}

// ---------------------------------------------------------------------------
extern "C" void kernel_launch(void* const* d_in, const int* in_sizes, int n_in,
                              void* d_out, int out_size, void* d_ws, size_t ws_size,
                              hipStream_t stream) {
  const float* E_char = (const float*)d_in[0];
  const float* W_ih_r = (const float*)d_in[1];
  const float* W_hh_r = (const float*)d_in[2];
  const float* b_r    = (const float*)d_in[3];
  const float* W_lat  = (const float*)d_in[4];
  const float* b_lat  = (const float*)d_in[5];
  const float* E_word = (const float*)d_in[6];
  const float* W_ih_w = (const float*)d_in[7];
  const float* W_hh_w = (const float*)d_in[8];
  const float* b_w    = (const float*)d_in[9];
  const int* word_ids = (const int*)d_in[10];
  const int* char_ids = (const int*)d_in[11];

  char* ws = (char*)d_ws;
  float*              tableR = (float*)(ws + 0x000000);              // 100 KB
  int*                electC = (int*)(ws + 0x020000);
  int*                electW = (int*)(ws + 0x020100);
  unsigned long long* slotC  = (unsigned long long*)(ws + 0x030000); // 64 KB
  unsigned long long* slotW  = (unsigned long long*)(ws + 0x050000); // 256 KB
  float*              h_word = (float*)(ws + 0x100000);              // 4 MB
  float*              latent = (float*)(ws + 0x500000);              // 2 MB
  float*              WT     = (float*)(ws + 0x700000);              // 2 MB
  float*              bperm  = (float*)(ws + 0x900000);              // 8 KB
  float*              Xw     = (float*)(ws + 0xA00000);              // 32 MB
  float* out = (float*)d_out;

  hipLaunchKernelGGL(k_init,      dim3(1),      dim3(64),  0, stream,
                     electC, electW);
  hipLaunchKernelGGL(k_table,     dim3(ALPHA),  dim3(256), 0, stream,
                     E_char, W_ih_r, b_r, tableR);
  hipLaunchKernelGGL(k_permw,     dim3(2048),   dim3(256), 0, stream,
                     W_ih_w, b_w, WT, bperm);
  hipLaunchKernelGGL(k_char_lstm, dim3(GRIDC),  dim3(256), 0, stream,
                     char_ids, W_hh_r, tableR, slotC, electC, h_word);
  hipLaunchKernelGGL(k_latent,    dim3(S_LEN),  dim3(128), 0, stream,
                     h_word, W_lat, b_lat, latent);
  hipLaunchKernelGGL(k_xw,        dim3(128, 8), dim3(256), 0, stream,
                     E_word, word_ids, latent, WT, bperm, Xw);
  hipLaunchKernelGGL(k_word_lstm, dim3(GRIDW),  dim3(512), 0, stream,
                     W_hh_w, Xw, slotW, electW, out);
}